// Round 2
// baseline (6784.661 us; speedup 1.0000x reference)
//
#include <hip/hip_runtime.h>
#include <hip/hip_bf16.h>

#define T_SEQ 512
#define NBATCH 64
#define HID 300
#define G4 1200
#define NTAG 11
#define TAG_START 9
#define TAG_STOP 10
#define NEGV -10000.0f
#define NWGD 38             // lstm WGs per direction, 8 hidden units (= 1 kblock) each
#define NKT 10              // k-tiles of 32 (K padded 300->320)
#define HXE (40*2*64*8)     // u16 per (dir,pp) hx buffer: 40 kblocks x {hi,lo} x 64 b x 8
#define NPREW 150           // companion pregemm WGs
#define FLGDIR (152*16)     // u32 stride per dir (layout kept; only first 256 used now)

typedef unsigned short u16;
using short8 = __attribute__((ext_vector_type(8))) short;
using f32x4  = __attribute__((ext_vector_type(4))) float;
using i32x4  = __attribute__((ext_vector_type(4))) int;

#define MF(a, b, c) __builtin_amdgcn_mfma_f32_16x16x32_bf16((a), (b), (c), 0, 0, 0)

__device__ __forceinline__ float sigf(float x) { return 1.0f / (1.0f + expf(-x)); }

__device__ __forceinline__ u16 f2bf(float x) {
    unsigned u = __float_as_uint(x);
    unsigned r = (u + 0x7FFFu + ((u >> 16) & 1u)) >> 16;   // RNE
    return (u16)r;
}
__device__ __forceinline__ float bf2f(u16 h) {
    return __uint_as_float((unsigned)h << 16);
}

// ---- LLC-coherent (fabric point) helpers: sc0 sc1, no cache-maintenance ops ----
__device__ __forceinline__ i32x4 ld_cc_x4(const u16* p) {
    i32x4 r;
    asm volatile("global_load_dwordx4 %0, %1, off sc0 sc1" : "=v"(r) : "v"(p) : "memory");
    return r;
}
__device__ __forceinline__ void st_cc_x4(u16* p, i32x4 v) {
    asm volatile("global_store_dwordx4 %0, %1, off sc0 sc1" :: "v"(p), "v"(v) : "memory");
}
__device__ __forceinline__ void st_cc_b32(unsigned* p, unsigned v) {
    asm volatile("global_store_dword %0, %1, off sc0 sc1" :: "v"(p), "v"(v) : "memory");
}
__device__ __forceinline__ void wait_vm0() {
    asm volatile("s_waitcnt vmcnt(0)" ::: "memory");
}

// ---------- embedding gather -> block layout xs0[t][40][64][2][8] (hi8|lo8 u16) ----------
__global__ __launch_bounds__(256) void k_gather(const int* __restrict__ x,
                                                const float* __restrict__ emb,
                                                u16* __restrict__ xs0)
{
    int t = blockIdx.x;
    __shared__ int rid[NBATCH];
    if (threadIdx.x < NBATCH) rid[threadIdx.x] = x[threadIdx.x * T_SEQ + t];
    __syncthreads();
    for (int o = threadIdx.x; o < 64 * 40; o += 256) {
        int b = o / 40, m8 = o - b * 40;
        unsigned hw[4], lw[4];
#pragma unroll
        for (int p = 0; p < 4; ++p) {
            int k0 = m8 * 8 + p * 2;
            float v0 = (k0 < 300)     ? emb[(size_t)rid[b] * 300 + k0]     : 0.0f;
            float v1 = (k0 + 1 < 300) ? emb[(size_t)rid[b] * 300 + k0 + 1] : 0.0f;
            u16 h0 = f2bf(v0), h1 = f2bf(v1);
            u16 l0 = f2bf(v0 - bf2f(h0)), l1 = f2bf(v1 - bf2f(h1));
            hw[p] = (unsigned)h0 | ((unsigned)h1 << 16);
            lw[p] = (unsigned)l0 | ((unsigned)l1 << 16);
        }
        u16* dst = xs0 + (((size_t)t * 40 + m8) * 64 + b) * 16;
        *(i32x4*)dst       = i32x4{(int)hw[0], (int)hw[1], (int)hw[2], (int)hw[3]};
        *(i32x4*)(dst + 8) = i32x4{(int)lw[0], (int)lw[1], (int)lw[2], (int)lw[3]};
    }
}

// ---------- zero xs1 pad blocks 76..79 ----------
__global__ __launch_bounds__(256) void k_zpad(u16* __restrict__ xs1)
{
    int t = blockIdx.x;
    i32x4* base = (i32x4*)(xs1 + (((size_t)t * 80 + 76) * 64) * 16);
    i32x4 z = {0, 0, 0, 0};
    for (int o = threadIdx.x; o < 4 * 64 * 2; o += 256) base[o] = z;
}

// ---------- pregemm core (device): one (jtile,dir), timesteps [s0,s1) ----------
template<int KT, int KMAX>
__device__ __forceinline__ void pregemm_role(
    const u16* __restrict__ xs,
    const float* __restrict__ Wi, const float* __restrict__ bi, const float* __restrict__ bh,
    float* __restrict__ pre, int jtile, int dir, int t0f, int t0b, int s0, int s1, int tid)
{
    int w = tid >> 6, l = tid & 63;
    int hh = l >> 4, kbx = l >> 4;
    int jj = jtile * 4 + hh;
    int bcol = w * 16 + (l & 15);

    short8 aH[KT], aL[KT];
    {
        int r = l & 15;
        int g = r & 3, uo = r >> 2;
        const float* wr = Wi + ((size_t)g * 300 + jtile * 4 + uo) * KMAX;
        int kb0 = kbx * 8;
#pragma unroll
        for (int kt = 0; kt < KT; ++kt) {
            short8 vh, vl;
#pragma unroll
            for (int e = 0; e < 8; ++e) {
                int kp = kt * 32 + kb0 + e;
                bool valid; int cc;
                if (KMAX == 600) { valid = (kp < 300) || (kp >= 304 && kp < 604); cc = (kp < 300) ? kp : kp - 4; }
                else             { valid = (kp < 300); cc = kp; }
                float wv = valid ? wr[cc] : 0.0f;
                u16 hb = f2bf(wv);
                vh[e] = (short)hb;
                vl[e] = (short)f2bf(wv - bf2f(hb));
            }
            aH[kt] = vh; aL[kt] = vl;
        }
    }
    float bias[4];
#pragma unroll
    for (int q = 0; q < 4; ++q) bias[q] = bi[q * 300 + jj] + bh[q * 300 + jj];

    const int NB8 = KT * 4;
    for (int s = s0; s < s1; ++s) {
        int t = dir ? (t0b - s) : (t0f + s);
        f32x4 a0 = {0.f,0.f,0.f,0.f}, a1 = {0.f,0.f,0.f,0.f}, a2 = {0.f,0.f,0.f,0.f};
#pragma unroll
        for (int kt = 0; kt < KT; ++kt) {
            const u16* gx = xs + (((size_t)t * NB8 + (4 * kt + kbx)) * 64 + bcol) * 16;
            short8 bhv = *(const short8*)gx;
            short8 blv = *(const short8*)(gx + 8);
            a0 = MF(aH[kt], bhv, a0);
            a1 = MF(aL[kt], bhv, a1);
            a2 = MF(aH[kt], blv, a2);
        }
#pragma unroll
        for (int q = 0; q < 4; ++q)
            pre[((size_t)s * G4 + q * 300 + jj) * 64 + bcol] = a0[q] + a1[q] + a2[q] + bias[q];
    }
}

// ---------- standalone pregemm (chunk 0 of each layer): sliced grid ----------
template<int KT, int KMAX>
__global__ __launch_bounds__(256) void k_pregemm(
    const u16* __restrict__ xs,
    const float* __restrict__ WiF, const float* __restrict__ WiB,
    const float* __restrict__ biF, const float* __restrict__ bhF,
    const float* __restrict__ biB, const float* __restrict__ bhB,
    float* __restrict__ preF, float* __restrict__ preB,
    int t0f, int t0b, int NSL, int C)
{
    int bx = blockIdx.x;
    int idx = bx / (2 * NSL);
    int rem = bx - idx * 2 * NSL;
    int sl = rem >> 1, dir = rem & 1;
    int s0 = sl * 32, s1 = min(s0 + 32, C);
    pregemm_role<KT, KMAX>(xs,
        dir ? WiB : WiF, dir ? biB : biF, dir ? bhB : bhF,
        dir ? preB : preF, idx, dir, t0f, t0b, s0, s1, threadIdx.x);
}

// ---------- lstm role: wave-autonomous flags + plane-split exchange ----------
// hx per (dir,pp): [kblock 0..39][plane hi/lo][batch 0..63][8 u16].
// Flags: per dir, packed region of 256 dwords = 4 wave-rows x 64; slot for
// (idx, w) is flg[w*64 + idx]. Poll semantics are IDENTICAL to the proven
// baseline (wait until ALL 152 wave-flags >= tgt), but the poll is one
// dwordx4 per lane over the packed region: 64 loads touching 16 cache lines
// per iteration, vs 192 loads / 152 lines in the 64B-strided scheme.
template<int MODE>
__device__ __forceinline__ void lstm_role(
    const float* __restrict__ preF, const float* __restrict__ preB,
    const float* __restrict__ WhF, const float* __restrict__ WhB,
    u16* __restrict__ hx, float* __restrict__ cbuf,
    float* __restrict__ xs2, u16* __restrict__ xs1,
    int t0f, int t0b, int C, int first,
    unsigned* __restrict__ flags,
    int bid, int tid)
{
    __builtin_amdgcn_s_setprio(1);
    int dir = bid & 1, idx = bid >> 1;   // idx 0..37
    const float* pre = dir ? preB : preF;
    const float* Wh  = dir ? WhB : WhF;
    u16* hxd = hx + (size_t)dir * 2 * HXE;
    float* cb = cbuf + (size_t)dir * 300 * 64;
    unsigned* flg = flags + (size_t)dir * FLGDIR;
    int w = tid >> 6, l = tid & 63;
    int hh = l >> 4, kbx = l >> 4;
    int bcol = w * 16 + (l & 15);
    int j0 = idx * 8;
    int ju0 = j0 + hh, ju1 = j0 + 4 + hh;
    int jc0 = min(ju0, 299), jc1 = min(ju1, 299);
    bool jv0 = ju0 < 300, jv1 = ju1 < 300;

    unsigned* myflag = flg + (size_t)w * 64 + idx;
    // poll: lane l covers flag-row (l>>4), flags (l&15)*4 .. +3
    const u16* polladdr = (const u16*)(flg + (size_t)l * 4);
    int pd0 = (l & 15) * 4;

    // A fragments (2 stripes x hi/lo), preloaded once
    short8 aH[2][NKT], aL[2][NKT];
    {
        int r = l & 15;
        int g = r & 3, uo = r >> 2;
#pragma unroll
        for (int q = 0; q < 2; ++q) {
            int jr = j0 + q * 4 + uo;
            const float* wr = Wh + ((size_t)g * 300 + min(jr, 299)) * 300;
            bool jvr = jr < 300;
#pragma unroll
            for (int kt = 0; kt < NKT; ++kt) {
                short8 vh, vl;
#pragma unroll
                for (int e = 0; e < 8; ++e) {
                    int k = kt * 32 + kbx * 8 + e;
                    float wv = (jvr && k < 300) ? wr[k] : 0.0f;
                    u16 hb = f2bf(wv);
                    vh[e] = (short)hb;
                    vl[e] = (short)f2bf(wv - bf2f(hb));
                }
                aH[q][kt] = vh; aL[q][kt] = vl;
            }
        }
    }
    float c0 = first ? 0.0f : cb[(size_t)jc0 * 64 + bcol];
    float c1 = first ? 0.0f : cb[(size_t)jc1 * 64 + bcol];

    float p0[4], p1[4];
#pragma unroll
    for (int g = 0; g < 4; ++g) {
        p0[g] = pre[((size_t)g * 300 + jc0) * 64 + bcol];
        p1[g] = pre[((size_t)g * 300 + jc1) * 64 + bcol];
    }

    int pp = 0;
    for (int s = 0; s < C; ++s) {
        f32x4 aA0 = {0.f,0.f,0.f,0.f}, aB0 = {0.f,0.f,0.f,0.f}, aC0 = {0.f,0.f,0.f,0.f};
        f32x4 aA1 = {0.f,0.f,0.f,0.f}, aB1 = {0.f,0.f,0.f,0.f}, aC1 = {0.f,0.f,0.f,0.f};
        if (!(first && s == 0)) {
            const u16* hxr = hxd + (size_t)pp * HXE;
            i32x4 bh[NKT], bl[NKT];
#pragma unroll
            for (int kt = 0; kt < NKT; ++kt) {
                const u16* gp = hxr + (size_t)(4 * kt + kbx) * 1024 + (size_t)bcol * 8;
                bh[kt] = ld_cc_x4(gp);
            }
#pragma unroll
            for (int kt = 0; kt < NKT; ++kt) {
                const u16* gp = hxr + (size_t)(4 * kt + kbx) * 1024 + (size_t)bcol * 8;
                bl[kt] = ld_cc_x4(gp + 512);
            }
            // hi plane ready (10 lo still in flight)
            asm volatile("s_waitcnt vmcnt(10)" ::: "memory");
            __builtin_amdgcn_sched_barrier(0);
#pragma unroll
            for (int kt = 0; kt < NKT; ++kt) {
                short8 bhv = __builtin_bit_cast(short8, bh[kt]);
                aA0 = MF(aH[0][kt], bhv, aA0);
                aB0 = MF(aL[0][kt], bhv, aB0);
                aA1 = MF(aH[1][kt], bhv, aA1);
                aB1 = MF(aL[1][kt], bhv, aB1);
            }
            wait_vm0();
            __builtin_amdgcn_sched_barrier(0);
#pragma unroll
            for (int kt = 0; kt < NKT; ++kt) {
                short8 blv = __builtin_bit_cast(short8, bl[kt]);
                aC0 = MF(aH[0][kt], blv, aC0);
                aC1 = MF(aH[1][kt], blv, aC1);
            }
        }
        float hv0, hv1;
        {
            float gi = sigf(aA0[0] + aB0[0] + aC0[0] + p0[0]);
            float gf = sigf(aA0[1] + aB0[1] + aC0[1] + p0[1]);
            float gg = tanhf(aA0[2] + aB0[2] + aC0[2] + p0[2]);
            float go = sigf(aA0[3] + aB0[3] + aC0[3] + p0[3]);
            c0 = gf * c0 + gi * gg;
            hv0 = go * tanhf(c0);
            if (!jv0) hv0 = 0.0f;
        }
        {
            float gi = sigf(aA1[0] + aB1[0] + aC1[0] + p1[0]);
            float gf = sigf(aA1[1] + aB1[1] + aC1[1] + p1[1]);
            float gg = tanhf(aA1[2] + aB1[2] + aC1[2] + p1[2]);
            float go = sigf(aA1[3] + aB1[3] + aC1[3] + p1[3]);
            c1 = gf * c1 + gi * gg;
            hv1 = go * tanhf(c1);
            if (!jv1) hv1 = 0.0f;
        }
        u16 hb0 = f2bf(hv0);
        unsigned pk0 = (unsigned)hb0 | ((unsigned)f2bf(hv0 - bf2f(hb0)) << 16);
        u16 hb1 = f2bf(hv1);
        unsigned pk1 = (unsigned)hb1 | ((unsigned)f2bf(hv1 - bf2f(hb1)) << 16);
        int ls = l & 15;
        unsigned a0 = __shfl(pk0, ls), a1 = __shfl(pk0, ls + 16), a2 = __shfl(pk0, ls + 32), a3 = __shfl(pk0, ls + 48);
        unsigned b0 = __shfl(pk1, ls), b1 = __shfl(pk1, ls + 16), b2 = __shfl(pk1, ls + 32), b3 = __shfl(pk1, ls + 48);
        i32x4 hi4 = {(int)((a0 & 0xffffu) | (a1 << 16)), (int)((a2 & 0xffffu) | (a3 << 16)),
                     (int)((b0 & 0xffffu) | (b1 << 16)), (int)((b2 & 0xffffu) | (b3 << 16))};
        i32x4 lo4 = {(int)((a0 >> 16) | (a1 & 0xffff0000u)), (int)((a2 >> 16) | (a3 & 0xffff0000u)),
                     (int)((b0 >> 16) | (b1 & 0xffff0000u)), (int)((b2 >> 16) | (b3 & 0xffff0000u))};
        int t = dir ? (t0b - s) : (t0f + s);
        // exchange stores (plane-split), wave-local drain, own flag — no syncthreads
        if (l < 16) {
            int b = w * 16 + l;
            u16* hxw = hxd + (size_t)(pp ^ 1) * HXE + (size_t)idx * 1024 + (size_t)b * 8;
            st_cc_x4(hxw, hi4);
            st_cc_x4(hxw + 512, lo4);
        }
        wait_vm0();
        if (l == 0) st_cc_b32(myflag, (unsigned)(s + 1));
        // xs output + next-step pre prefetch (drain under the poll)
        if (MODE == 0) {
            if (jv0) xs2[((size_t)t * 600 + dir * 300 + ju0) * 64 + bcol] = hv0;
            if (jv1) xs2[((size_t)t * 600 + dir * 300 + ju1) * 64 + bcol] = hv1;
        } else if (l < 16) {
            int b = w * 16 + l;
            u16* xd = xs1 + (((size_t)t * 80 + dir * 38 + idx) * 64 + b) * 16;
            *(i32x4*)xd       = hi4;
            *(i32x4*)(xd + 8) = lo4;
        }
        if (s + 1 < C) {
#pragma unroll
            for (int g = 0; g < 4; ++g) {
                p0[g] = pre[((size_t)(s + 1) * G4 + (size_t)g * 300 + jc0) * 64 + bcol];
                p1[g] = pre[((size_t)(s + 1) * G4 + (size_t)g * 300 + jc1) * 64 + bcol];
            }
            unsigned tgt = (unsigned)(s + 1);
            unsigned ok;
            do {
                i32x4 v = ld_cc_x4(polladdr);
                wait_vm0();
                ok = (((unsigned)v[0] >= tgt) || (pd0 + 0 >= 38)) &&
                     (((unsigned)v[1] >= tgt) || (pd0 + 1 >= 38)) &&
                     (((unsigned)v[2] >= tgt) || (pd0 + 2 >= 38)) &&
                     (((unsigned)v[3] >= tgt) || (pd0 + 3 >= 38));
            } while (!__all(ok));
        }
        pp ^= 1;
    }
    if (jv0) cb[(size_t)jc0 * 64 + bcol] = c0;
    if (jv1) cb[(size_t)jc1 * 64 + bcol] = c1;
}

// ---------- fused chunk kernel: 76 lstm WGs + 150 companion pregemm WGs ----------
template<int KT, int KMAX, int MODE>
__global__ __launch_bounds__(256, 1) void k_chunk(
    const u16* __restrict__ xsN,
    const float* __restrict__ WiF, const float* __restrict__ WiB,
    const float* __restrict__ biF, const float* __restrict__ bhF,
    const float* __restrict__ biB, const float* __restrict__ bhB,
    float* __restrict__ preNF, float* __restrict__ preNB,
    int t0fN, int t0bN, int do_pre, int CN,
    const float* __restrict__ preF, const float* __restrict__ preB,
    const float* __restrict__ WhF, const float* __restrict__ WhB,
    u16* __restrict__ hx, float* __restrict__ cbuf,
    float* __restrict__ xs2, u16* __restrict__ xs1,
    int t0f, int t0b, int C, int first,
    unsigned* __restrict__ flags)
{
    int bid = blockIdx.x;
    if (bid < 2 * NWGD) {
        lstm_role<MODE>(preF, preB, WhF, WhB, hx, cbuf, xs2, xs1,
                        t0f, t0b, C, first, flags, bid, threadIdx.x);
    } else if (do_pre) {
        int wg = bid - 2 * NWGD;         // 0..149
        int jtile = wg >> 1, dir = wg & 1;
        pregemm_role<KT, KMAX>(xsN,
            dir ? WiB : WiF, dir ? biB : biF, dir ? bhB : bhF,
            dir ? preNB : preNF, jtile, dir, t0fN, t0bN, 0, CN, threadIdx.x);
    }
}

// ---------- output projection: feats[t][g][b] ----------
__global__ __launch_bounds__(256) void k_feats(
    const float* __restrict__ xs2, const float* __restrict__ Wout,
    const float* __restrict__ bout, float* __restrict__ feats)
{
    int t = blockIdx.x;
    int tid = threadIdx.x;
    int b = tid & 63, g0 = tid >> 6;
    const float* xa = xs2 + (size_t)t * 600 * 64 + b;
    for (int g = g0; g < NTAG; g += 4) {
        float acc = bout[g];
        const float* wr = Wout + (size_t)g * 600;
#pragma unroll 4
        for (int k = 0; k < 600; ++k) acc += wr[k] * xa[(size_t)k * 64];
        feats[((size_t)t * NTAG + g) * 64 + b] = acc;
    }
}

// ---------- Viterbi ----------
__global__ __launch_bounds__(256) void k_viterbi(
    const float* __restrict__ feats, const float* __restrict__ trans,
    float* __restrict__ out)
{
    __shared__ unsigned char bp[4][T_SEQ * NTAG];
    int tid = threadIdx.x;
    int wv = tid >> 6, lane = tid & 63;
    int b = blockIdx.x * 4 + wv;
    int i = (lane < NTAG) ? lane : 0;
    bool act = lane < NTAG;
    float trow[NTAG];
#pragma unroll
    for (int j = 0; j < NTAG; ++j) trow[j] = trans[i * NTAG + j];
    float fv = (lane == TAG_START) ? 0.0f : NEGV;
    for (int t = 0; t < T_SEQ; ++t) {
        float m = -3.0e38f; int arg = 0;
#pragma unroll
        for (int j = 0; j < NTAG; ++j) {
            float fvj = __shfl(fv, j, 64);
            float sc = fvj + trow[j];
            if (sc > m) { m = sc; arg = j; }
        }
        float ft = feats[((size_t)t * NTAG + i) * 64 + b];
        fv = m + ft;
        if (act) bp[wv][t * NTAG + lane] = (unsigned char)arg;
    }
    float term = act ? (fv + trans[TAG_STOP * NTAG + i]) : -3.0e38f;
    int bi_ = lane;
#pragma unroll
    for (int off = 32; off >= 1; off >>= 1) {
        float ov = __shfl_xor(term, off, 64);
        int oi = __shfl_xor(bi_, off, 64);
        if (ov > term || (ov == term && oi < bi_)) { term = ov; bi_ = oi; }
    }
    if (lane == 0) {
        out[b] = term;
        int tag = bi_;
        float* po = out + 64 + (size_t)b * T_SEQ;
        for (int t = T_SEQ - 1; t >= 0; --t) {
            po[t] = (float)tag;
            tag = bp[wv][t * NTAG + tag];
        }
    }
}

extern "C" void kernel_launch(void* const* d_in, const int* in_sizes, int n_in,
                              void* d_out, int out_size, void* d_ws, size_t ws_size,
                              hipStream_t stream)
{
    (void)in_sizes; (void)n_in; (void)out_size;
    const int*   x     = (const int*)d_in[0];
    const float* emb   = (const float*)d_in[1];
    const float* Wout  = (const float*)d_in[2];
    const float* bout  = (const float*)d_in[3];
    const float* trans = (const float*)d_in[4];

    float* ws = (float*)d_ws;
    const size_t XS2F = (size_t)T_SEQ * 600 * NBATCH;          // f32
    const size_t XS1U = (size_t)T_SEQ * 80 * 64 * 16;          // u16
    const size_t FEA  = (size_t)T_SEQ * NTAG * NBATCH;

    float* xs2 = ws;                          // layer-1 f32 output (aliases xs0 blocks)
    u16* xs0 = (u16*)ws;                      // [T][40][64][2][8]
    u16* xs1 = (u16*)(ws + XS2F);             // [T][80][64][2][8]
    float* featB = (float*)(xs1 + XS1U);
    float* cB = featB + FEA;                  // 2*300*64
    u16* hxB = (u16*)(cB + 2 * 300 * 64);     // 4*HXE
    unsigned* flagsB = (unsigned*)(hxB + 4 * HXE);   // 64 slots * 2 dirs * FLGDIR
    unsigned* padB = flagsB + 64ULL * 2 * FLGDIR;    // layout hole kept (16 u32)
    float* preBase = (float*)(padB + 16);
    size_t fixedBytes = (size_t)((char*)preBase - (char*)ws);

    // two ping-pong pre slots; each slot = preF+preB = 2*Cmax*G4*64 floats
    int Cmax = 512;
    while (Cmax > 16 && fixedBytes + 4ULL * Cmax * G4 * NBATCH * 4ULL > ws_size) Cmax >>= 1;
    size_t slotF = 2ULL * Cmax * G4 * NBATCH;
    float* preS[2] = { preBase, preBase + slotF };

    // chunk schedule: small first chunk shrinks the exposed standalone pregemm
    int sizes[40], off[41], nch = 0;
    {
        int rem = T_SEQ;
        int f = (Cmax >= 64) ? 32 : Cmax;
        sizes[nch++] = f; rem -= f;
        while (rem > 0) { int s = rem < Cmax ? rem : Cmax; sizes[nch++] = s; rem -= s; }
        off[0] = 0;
        for (int i = 0; i < nch; ++i) off[i + 1] = off[i] + sizes[i];
    }

    (void)hipMemsetAsync(hxB, 0,
        4 * HXE * sizeof(u16) + (64ULL * 2 * FLGDIR) * sizeof(unsigned), stream);
    k_gather<<<T_SEQ, 256, 0, stream>>>(x, emb, xs0);
    k_zpad<<<T_SEQ, 256, 0, stream>>>(xs1);

    for (int layer = 0; layer < 2; ++layer) {
        int base = 5 + layer * 8;
        const float* WiF = (const float*)d_in[base + 0];
        const float* WhF = (const float*)d_in[base + 1];
        const float* biF = (const float*)d_in[base + 2];
        const float* bhF = (const float*)d_in[base + 3];
        const float* WiB = (const float*)d_in[base + 4];
        const float* WhB = (const float*)d_in[base + 5];
        const float* biB = (const float*)d_in[base + 6];
        const float* bhB = (const float*)d_in[base + 7];

        int NSL0 = (sizes[0] + 31) / 32;
        if (layer == 0)
            k_pregemm<10, 300><<<75 * 2 * NSL0, 256, 0, stream>>>(
                xs0, WiF, WiB, biF, bhF, biB, bhB,
                preS[0], preS[0] + slotF / 2, 0, T_SEQ - 1, NSL0, sizes[0]);
        else
            k_pregemm<20, 600><<<75 * 2 * NSL0, 256, 0, stream>>>(
                xs1, WiF, WiB, biF, bhF, biB, bhB,
                preS[0], preS[0] + slotF / 2, 0, T_SEQ - 1, NSL0, sizes[0]);

        for (int ci = 0; ci < nch; ++ci) {
            int cur = ci & 1, nxt = cur ^ 1;
            int t0f = off[ci], t0b = (T_SEQ - 1) - off[ci];
            int do_pre = (ci + 1 < nch) ? 1 : 0;
            int CN = do_pre ? sizes[ci + 1] : 0;
            int t0fN = off[ci + 1], t0bN = (T_SEQ - 1) - off[ci + 1];
            int slot = layer * 32 + ci;
            unsigned* flags = flagsB + (size_t)slot * 2 * FLGDIR;
            if (layer == 0)
                k_chunk<10, 300, 1><<<2 * NWGD + NPREW, 256, 0, stream>>>(
                    xs0, WiF, WiB, biF, bhF, biB, bhB,
                    preS[nxt], preS[nxt] + slotF / 2, t0fN, t0bN, do_pre, CN,
                    preS[cur], preS[cur] + slotF / 2, WhF, WhB, hxB, cB,
                    xs2, xs1, t0f, t0b, sizes[ci], (ci == 0) ? 1 : 0, flags);
            else
                k_chunk<20, 600, 0><<<2 * NWGD + NPREW, 256, 0, stream>>>(
                    xs1, WiF, WiB, biF, bhF, biB, bhB,
                    preS[nxt], preS[nxt] + slotF / 2, t0fN, t0bN, do_pre, CN,
                    preS[cur], preS[cur] + slotF / 2, WhF, WhB, hxB, cB,
                    xs2, xs1, t0f, t0b, sizes[ci], (ci == 0) ? 1 : 0, flags);
        }
    }
    k_feats<<<T_SEQ, 256, 0, stream>>>(xs2, Wout, bout, featB);
    k_viterbi<<<16, 256, 0, stream>>>(featB, trans, (float*)d_out);
}

// Round 3
// 6394.054 us; speedup vs baseline: 1.0611x; 1.0611x over previous
//
#include <hip/hip_runtime.h>
#include <hip/hip_bf16.h>

#define T_SEQ 512
#define NBATCH 64
#define HID 300
#define G4 1200
#define NTAG 11
#define TAG_START 9
#define TAG_STOP 10
#define NEGV -10000.0f
#define NWGD 38             // lstm WGs per direction, 8 hidden units (= 1 kblock) each
#define NKT 10              // k-tiles of 32 (K padded 300->320)
#define HXE (40*2*64*8)     // u16 per (dir,pp) hx buffer: 40 kblocks x {hi,lo} x 64 b x 8
#define NPREW 150           // companion pregemm WGs
#define FLGS 16             // u32 stride between flags (64B slots)
#define FLGN 152            // flags per dir = 38 WGs x 4 waves
#define FLGDIR (FLGN*FLGS)
#define PACE_SLACK 8        // pregemm may run this many (scaled) steps ahead of lstm

typedef unsigned short u16;
using short8 = __attribute__((ext_vector_type(8))) short;
using f32x4  = __attribute__((ext_vector_type(4))) float;
using i32x4  = __attribute__((ext_vector_type(4))) int;

#define MF(a, b, c) __builtin_amdgcn_mfma_f32_16x16x32_bf16((a), (b), (c), 0, 0, 0)

__device__ __forceinline__ float sigf(float x) { return 1.0f / (1.0f + expf(-x)); }

__device__ __forceinline__ u16 f2bf(float x) {
    unsigned u = __float_as_uint(x);
    unsigned r = (u + 0x7FFFu + ((u >> 16) & 1u)) >> 16;   // RNE
    return (u16)r;
}
__device__ __forceinline__ float bf2f(u16 h) {
    return __uint_as_float((unsigned)h << 16);
}

// ---- LLC-coherent (fabric point) helpers: sc0 sc1, no cache-maintenance ops ----
__device__ __forceinline__ i32x4 ld_cc_x4(const u16* p) {
    i32x4 r;
    asm volatile("global_load_dwordx4 %0, %1, off sc0 sc1" : "=v"(r) : "v"(p) : "memory");
    return r;
}
__device__ __forceinline__ unsigned ld_cc_b32(const unsigned* p) {
    unsigned r;
    asm volatile("global_load_dword %0, %1, off sc0 sc1\n\t"
                 "s_waitcnt vmcnt(0)" : "=v"(r) : "v"(p) : "memory");
    return r;
}
__device__ __forceinline__ void st_cc_x4(u16* p, i32x4 v) {
    asm volatile("global_store_dwordx4 %0, %1, off sc0 sc1" :: "v"(p), "v"(v) : "memory");
}
__device__ __forceinline__ void st_cc_b32(unsigned* p, unsigned v) {
    asm volatile("global_store_dword %0, %1, off sc0 sc1" :: "v"(p), "v"(v) : "memory");
}
__device__ __forceinline__ void wait_vm0() {
    asm volatile("s_waitcnt vmcnt(0)" ::: "memory");
}
// fused 3-flag poll: 3 loads, one drain, compare
__device__ __forceinline__ unsigned poll3(const unsigned* a, const unsigned* b,
                                          const unsigned* c, unsigned tgt) {
    unsigned r0, r1, r2;
    asm volatile(
        "global_load_dword %0, %3, off sc0 sc1\n\t"
        "global_load_dword %1, %4, off sc0 sc1\n\t"
        "global_load_dword %2, %5, off sc0 sc1\n\t"
        "s_waitcnt vmcnt(0)"
        : "=&v"(r0), "=&v"(r1), "=&v"(r2)
        : "v"(a), "v"(b), "v"(c)
        : "memory");
    return (r0 >= tgt && r1 >= tgt && r2 >= tgt) ? 1u : 0u;
}

// ---------- embedding gather -> block layout xs0[t][40][64][2][8] (hi8|lo8 u16) ----------
__global__ __launch_bounds__(256) void k_gather(const int* __restrict__ x,
                                                const float* __restrict__ emb,
                                                u16* __restrict__ xs0)
{
    int t = blockIdx.x;
    __shared__ int rid[NBATCH];
    if (threadIdx.x < NBATCH) rid[threadIdx.x] = x[threadIdx.x * T_SEQ + t];
    __syncthreads();
    for (int o = threadIdx.x; o < 64 * 40; o += 256) {
        int b = o / 40, m8 = o - b * 40;
        unsigned hw[4], lw[4];
#pragma unroll
        for (int p = 0; p < 4; ++p) {
            int k0 = m8 * 8 + p * 2;
            float v0 = (k0 < 300)     ? emb[(size_t)rid[b] * 300 + k0]     : 0.0f;
            float v1 = (k0 + 1 < 300) ? emb[(size_t)rid[b] * 300 + k0 + 1] : 0.0f;
            u16 h0 = f2bf(v0), h1 = f2bf(v1);
            u16 l0 = f2bf(v0 - bf2f(h0)), l1 = f2bf(v1 - bf2f(h1));
            hw[p] = (unsigned)h0 | ((unsigned)h1 << 16);
            lw[p] = (unsigned)l0 | ((unsigned)l1 << 16);
        }
        u16* dst = xs0 + (((size_t)t * 40 + m8) * 64 + b) * 16;
        *(i32x4*)dst       = i32x4{(int)hw[0], (int)hw[1], (int)hw[2], (int)hw[3]};
        *(i32x4*)(dst + 8) = i32x4{(int)lw[0], (int)lw[1], (int)lw[2], (int)lw[3]};
    }
}

// ---------- zero xs1 pad blocks 76..79 ----------
__global__ __launch_bounds__(256) void k_zpad(u16* __restrict__ xs1)
{
    int t = blockIdx.x;
    i32x4* base = (i32x4*)(xs1 + (((size_t)t * 80 + 76) * 64) * 16);
    i32x4 z = {0, 0, 0, 0};
    for (int o = threadIdx.x; o < 4 * 64 * 2; o += 256) base[o] = z;
}

// ---------- pregemm core (device): one (jtile,dir), timesteps [s0,s1) ----------
// pace != nullptr (companion mode): throttle so this WG stays <= PACE_SLACK
// (scaled) steps ahead of the live lstm recurrence. This keeps all 150
// companion WGs walking the xs stream inside a small window (XCD-L2
// resident) instead of streaming 12-24 MB/step through the LLC/fabric,
// which inflates the latency of the lstm's device-scope sync ops.
template<int KT, int KMAX>
__device__ __forceinline__ void pregemm_role(
    const u16* __restrict__ xs,
    const float* __restrict__ Wi, const float* __restrict__ bi, const float* __restrict__ bh,
    float* __restrict__ pre, int jtile, int dir, int t0f, int t0b, int s0, int s1, int tid,
    const unsigned* __restrict__ pace, int Ccur)
{
    int w = tid >> 6, l = tid & 63;
    int hh = l >> 4, kbx = l >> 4;
    int jj = jtile * 4 + hh;
    int bcol = w * 16 + (l & 15);

    short8 aH[KT], aL[KT];
    {
        int r = l & 15;
        int g = r & 3, uo = r >> 2;
        const float* wr = Wi + ((size_t)g * 300 + jtile * 4 + uo) * KMAX;
        int kb0 = kbx * 8;
#pragma unroll
        for (int kt = 0; kt < KT; ++kt) {
            short8 vh, vl;
#pragma unroll
            for (int e = 0; e < 8; ++e) {
                int kp = kt * 32 + kb0 + e;
                bool valid; int cc;
                if (KMAX == 600) { valid = (kp < 300) || (kp >= 304 && kp < 604); cc = (kp < 300) ? kp : kp - 4; }
                else             { valid = (kp < 300); cc = kp; }
                float wv = valid ? wr[cc] : 0.0f;
                u16 hb = f2bf(wv);
                vh[e] = (short)hb;
                vl[e] = (short)f2bf(wv - bf2f(hb));
            }
            aH[kt] = vh; aL[kt] = vl;
        }
    }
    float bias[4];
#pragma unroll
    for (int q = 0; q < 4; ++q) bias[q] = bi[q * 300 + jj] + bh[q * 300 + jj];

    const int NB8 = KT * 4;
    for (int s = s0; s < s1; ++s) {
        if (pace) {
            // lstm must have completed step `need` before we process step s
            int need = (int)(((long long)s * Ccur) / s1) - PACE_SLACK;
            if (need > 0) {
                unsigned fv = ld_cc_b32(pace);
                while ((int)fv < need) {
                    __builtin_amdgcn_s_sleep(8);
                    fv = ld_cc_b32(pace);
                }
            }
        }
        int t = dir ? (t0b - s) : (t0f + s);
        f32x4 a0 = {0.f,0.f,0.f,0.f}, a1 = {0.f,0.f,0.f,0.f}, a2 = {0.f,0.f,0.f,0.f};
#pragma unroll
        for (int kt = 0; kt < KT; ++kt) {
            const u16* gx = xs + (((size_t)t * NB8 + (4 * kt + kbx)) * 64 + bcol) * 16;
            short8 bhv = *(const short8*)gx;
            short8 blv = *(const short8*)(gx + 8);
            a0 = MF(aH[kt], bhv, a0);
            a1 = MF(aL[kt], bhv, a1);
            a2 = MF(aH[kt], blv, a2);
        }
#pragma unroll
        for (int q = 0; q < 4; ++q)
            pre[((size_t)s * G4 + q * 300 + jj) * 64 + bcol] = a0[q] + a1[q] + a2[q] + bias[q];
    }
}

// ---------- standalone pregemm (chunk 0 of each layer): sliced grid ----------
template<int KT, int KMAX>
__global__ __launch_bounds__(256) void k_pregemm(
    const u16* __restrict__ xs,
    const float* __restrict__ WiF, const float* __restrict__ WiB,
    const float* __restrict__ biF, const float* __restrict__ bhF,
    const float* __restrict__ biB, const float* __restrict__ bhB,
    float* __restrict__ preF, float* __restrict__ preB,
    int t0f, int t0b, int NSL, int C)
{
    int bx = blockIdx.x;
    int idx = bx / (2 * NSL);
    int rem = bx - idx * 2 * NSL;
    int sl = rem >> 1, dir = rem & 1;
    int s0 = sl * 32, s1 = min(s0 + 32, C);
    pregemm_role<KT, KMAX>(xs,
        dir ? WiB : WiF, dir ? biB : biF, dir ? bhB : bhF,
        dir ? preB : preF, idx, dir, t0f, t0b, s0, s1, threadIdx.x,
        nullptr, 0);
}

// ---------- lstm role: wave-autonomous flags + plane-split exchange ----------
// hx per (dir,pp): [kblock 0..39][plane hi/lo][batch 0..63][8 u16]. Consumer
// instruction footprint = 256B contiguous per 16-lane group (2 lines, was 4).
template<int MODE>
__device__ __forceinline__ void lstm_role(
    const float* __restrict__ preF, const float* __restrict__ preB,
    const float* __restrict__ WhF, const float* __restrict__ WhB,
    u16* __restrict__ hx, float* __restrict__ cbuf,
    float* __restrict__ xs2, u16* __restrict__ xs1,
    int t0f, int t0b, int C, int first,
    unsigned* __restrict__ flags, const unsigned* __restrict__ pad,
    int bid, int tid)
{
    __builtin_amdgcn_s_setprio(1);
    int dir = bid & 1, idx = bid >> 1;   // idx 0..37
    const float* pre = dir ? preB : preF;
    const float* Wh  = dir ? WhB : WhF;
    u16* hxd = hx + (size_t)dir * 2 * HXE;
    float* cb = cbuf + (size_t)dir * 300 * 64;
    unsigned* flg = flags + (size_t)dir * FLGDIR;
    int w = tid >> 6, l = tid & 63;
    int hh = l >> 4, kbx = l >> 4;
    int bcol = w * 16 + (l & 15);
    int j0 = idx * 8;
    int ju0 = j0 + hh, ju1 = j0 + 4 + hh;
    int jc0 = min(ju0, 299), jc1 = min(ju1, 299);
    bool jv0 = ju0 < 300, jv1 = ju1 < 300;

    unsigned* myflag = flg + (size_t)(idx * 4 + w) * FLGS;
    const unsigned* pa = flg + (size_t)l * FLGS;
    const unsigned* pb = flg + (size_t)(l + 64) * FLGS;
    const unsigned* pcf = (l < FLGN - 128) ? (const unsigned*)(flg + (size_t)(l + 128) * FLGS) : pad;

    // A fragments (2 stripes x hi/lo), preloaded once
    short8 aH[2][NKT], aL[2][NKT];
    {
        int r = l & 15;
        int g = r & 3, uo = r >> 2;
#pragma unroll
        for (int q = 0; q < 2; ++q) {
            int jr = j0 + q * 4 + uo;
            const float* wr = Wh + ((size_t)g * 300 + min(jr, 299)) * 300;
            bool jvr = jr < 300;
#pragma unroll
            for (int kt = 0; kt < NKT; ++kt) {
                short8 vh, vl;
#pragma unroll
                for (int e = 0; e < 8; ++e) {
                    int k = kt * 32 + kbx * 8 + e;
                    float wv = (jvr && k < 300) ? wr[k] : 0.0f;
                    u16 hb = f2bf(wv);
                    vh[e] = (short)hb;
                    vl[e] = (short)f2bf(wv - bf2f(hb));
                }
                aH[q][kt] = vh; aL[q][kt] = vl;
            }
        }
    }
    float c0 = first ? 0.0f : cb[(size_t)jc0 * 64 + bcol];
    float c1 = first ? 0.0f : cb[(size_t)jc1 * 64 + bcol];

    float p0[4], p1[4];
#pragma unroll
    for (int g = 0; g < 4; ++g) {
        p0[g] = pre[((size_t)g * 300 + jc0) * 64 + bcol];
        p1[g] = pre[((size_t)g * 300 + jc1) * 64 + bcol];
    }

    int pp = 0;
    for (int s = 0; s < C; ++s) {
        f32x4 aA0 = {0.f,0.f,0.f,0.f}, aB0 = {0.f,0.f,0.f,0.f}, aC0 = {0.f,0.f,0.f,0.f};
        f32x4 aA1 = {0.f,0.f,0.f,0.f}, aB1 = {0.f,0.f,0.f,0.f}, aC1 = {0.f,0.f,0.f,0.f};
        if (!(first && s == 0)) {
            const u16* hxr = hxd + (size_t)pp * HXE;
            i32x4 bh[NKT], bl[NKT];
#pragma unroll
            for (int kt = 0; kt < NKT; ++kt) {
                const u16* gp = hxr + (size_t)(4 * kt + kbx) * 1024 + (size_t)bcol * 8;
                bh[kt] = ld_cc_x4(gp);
            }
#pragma unroll
            for (int kt = 0; kt < NKT; ++kt) {
                const u16* gp = hxr + (size_t)(4 * kt + kbx) * 1024 + (size_t)bcol * 8;
                bl[kt] = ld_cc_x4(gp + 512);
            }
            // hi plane ready (10 lo still in flight)
            asm volatile("s_waitcnt vmcnt(10)" ::: "memory");
            __builtin_amdgcn_sched_barrier(0);
#pragma unroll
            for (int kt = 0; kt < NKT; ++kt) {
                short8 bhv = __builtin_bit_cast(short8, bh[kt]);
                aA0 = MF(aH[0][kt], bhv, aA0);
                aB0 = MF(aL[0][kt], bhv, aB0);
                aA1 = MF(aH[1][kt], bhv, aA1);
                aB1 = MF(aL[1][kt], bhv, aB1);
            }
            wait_vm0();
            __builtin_amdgcn_sched_barrier(0);
#pragma unroll
            for (int kt = 0; kt < NKT; ++kt) {
                short8 blv = __builtin_bit_cast(short8, bl[kt]);
                aC0 = MF(aH[0][kt], blv, aC0);
                aC1 = MF(aH[1][kt], blv, aC1);
            }
        }
        float hv0, hv1;
        {
            float gi = sigf(aA0[0] + aB0[0] + aC0[0] + p0[0]);
            float gf = sigf(aA0[1] + aB0[1] + aC0[1] + p0[1]);
            float gg = tanhf(aA0[2] + aB0[2] + aC0[2] + p0[2]);
            float go = sigf(aA0[3] + aB0[3] + aC0[3] + p0[3]);
            c0 = gf * c0 + gi * gg;
            hv0 = go * tanhf(c0);
            if (!jv0) hv0 = 0.0f;
        }
        {
            float gi = sigf(aA1[0] + aB1[0] + aC1[0] + p1[0]);
            float gf = sigf(aA1[1] + aB1[1] + aC1[1] + p1[1]);
            float gg = tanhf(aA1[2] + aB1[2] + aC1[2] + p1[2]);
            float go = sigf(aA1[3] + aB1[3] + aC1[3] + p1[3]);
            c1 = gf * c1 + gi * gg;
            hv1 = go * tanhf(c1);
            if (!jv1) hv1 = 0.0f;
        }
        u16 hb0 = f2bf(hv0);
        unsigned pk0 = (unsigned)hb0 | ((unsigned)f2bf(hv0 - bf2f(hb0)) << 16);
        u16 hb1 = f2bf(hv1);
        unsigned pk1 = (unsigned)hb1 | ((unsigned)f2bf(hv1 - bf2f(hb1)) << 16);
        int ls = l & 15;
        unsigned a0 = __shfl(pk0, ls), a1 = __shfl(pk0, ls + 16), a2 = __shfl(pk0, ls + 32), a3 = __shfl(pk0, ls + 48);
        unsigned b0 = __shfl(pk1, ls), b1 = __shfl(pk1, ls + 16), b2 = __shfl(pk1, ls + 32), b3 = __shfl(pk1, ls + 48);
        i32x4 hi4 = {(int)((a0 & 0xffffu) | (a1 << 16)), (int)((a2 & 0xffffu) | (a3 << 16)),
                     (int)((b0 & 0xffffu) | (b1 << 16)), (int)((b2 & 0xffffu) | (b3 << 16))};
        i32x4 lo4 = {(int)((a0 >> 16) | (a1 & 0xffff0000u)), (int)((a2 >> 16) | (a3 & 0xffff0000u)),
                     (int)((b0 >> 16) | (b1 & 0xffff0000u)), (int)((b2 >> 16) | (b3 & 0xffff0000u))};
        int t = dir ? (t0b - s) : (t0f + s);
        // exchange stores (plane-split), wave-local drain, own flag — no syncthreads
        if (l < 16) {
            int b = w * 16 + l;
            u16* hxw = hxd + (size_t)(pp ^ 1) * HXE + (size_t)idx * 1024 + (size_t)b * 8;
            st_cc_x4(hxw, hi4);
            st_cc_x4(hxw + 512, lo4);
        }
        wait_vm0();
        if (l == 0) st_cc_b32(myflag, (unsigned)(s + 1));
        // xs output + next-step pre prefetch (drain under the poll)
        if (MODE == 0) {
            if (jv0) xs2[((size_t)t * 600 + dir * 300 + ju0) * 64 + bcol] = hv0;
            if (jv1) xs2[((size_t)t * 600 + dir * 300 + ju1) * 64 + bcol] = hv1;
        } else if (l < 16) {
            int b = w * 16 + l;
            u16* xd = xs1 + (((size_t)t * 80 + dir * 38 + idx) * 64 + b) * 16;
            *(i32x4*)xd       = hi4;
            *(i32x4*)(xd + 8) = lo4;
        }
        if (s + 1 < C) {
#pragma unroll
            for (int g = 0; g < 4; ++g) {
                p0[g] = pre[((size_t)(s + 1) * G4 + (size_t)g * 300 + jc0) * 64 + bcol];
                p1[g] = pre[((size_t)(s + 1) * G4 + (size_t)g * 300 + jc1) * 64 + bcol];
            }
            unsigned ok;
            do { ok = poll3(pa, pb, pcf, (unsigned)(s + 1)); } while (!__all(ok));
        }
        pp ^= 1;
    }
    if (jv0) cb[(size_t)jc0 * 64 + bcol] = c0;
    if (jv1) cb[(size_t)jc1 * 64 + bcol] = c1;
}

// ---------- fused chunk kernel: 76 lstm WGs + 150 companion pregemm WGs ----------
template<int KT, int KMAX, int MODE>
__global__ __launch_bounds__(256, 1) void k_chunk(
    const u16* __restrict__ xsN,
    const float* __restrict__ WiF, const float* __restrict__ WiB,
    const float* __restrict__ biF, const float* __restrict__ bhF,
    const float* __restrict__ biB, const float* __restrict__ bhB,
    float* __restrict__ preNF, float* __restrict__ preNB,
    int t0fN, int t0bN, int do_pre, int CN,
    const float* __restrict__ preF, const float* __restrict__ preB,
    const float* __restrict__ WhF, const float* __restrict__ WhB,
    u16* __restrict__ hx, float* __restrict__ cbuf,
    float* __restrict__ xs2, u16* __restrict__ xs1,
    int t0f, int t0b, int C, int first,
    unsigned* __restrict__ flags, const unsigned* __restrict__ pad)
{
    int bid = blockIdx.x;
    if (bid < 2 * NWGD) {
        lstm_role<MODE>(preF, preB, WhF, WhB, hx, cbuf, xs2, xs1,
                        t0f, t0b, C, first, flags, pad, bid, threadIdx.x);
    } else if (do_pre) {
        int wg = bid - 2 * NWGD;         // 0..149
        int jtile = wg >> 1, dir = wg & 1;
        const unsigned* pace = flags + (size_t)dir * FLGDIR;   // flag of (idx0, w0)
        pregemm_role<KT, KMAX>(xsN,
            dir ? WiB : WiF, dir ? biB : biF, dir ? bhB : bhF,
            dir ? preNB : preNF, jtile, dir, t0fN, t0bN, 0, CN, threadIdx.x,
            pace, C);
    }
}

// ---------- output projection: feats[t][g][b] ----------
__global__ __launch_bounds__(256) void k_feats(
    const float* __restrict__ xs2, const float* __restrict__ Wout,
    const float* __restrict__ bout, float* __restrict__ feats)
{
    int t = blockIdx.x;
    int tid = threadIdx.x;
    int b = tid & 63, g0 = tid >> 6;
    const float* xa = xs2 + (size_t)t * 600 * 64 + b;
    for (int g = g0; g < NTAG; g += 4) {
        float acc = bout[g];
        const float* wr = Wout + (size_t)g * 600;
#pragma unroll 4
        for (int k = 0; k < 600; ++k) acc += wr[k] * xa[(size_t)k * 64];
        feats[((size_t)t * NTAG + g) * 64 + b] = acc;
    }
}

// ---------- Viterbi ----------
__global__ __launch_bounds__(256) void k_viterbi(
    const float* __restrict__ feats, const float* __restrict__ trans,
    float* __restrict__ out)
{
    __shared__ unsigned char bp[4][T_SEQ * NTAG];
    int tid = threadIdx.x;
    int wv = tid >> 6, lane = tid & 63;
    int b = blockIdx.x * 4 + wv;
    int i = (lane < NTAG) ? lane : 0;
    bool act = lane < NTAG;
    float trow[NTAG];
#pragma unroll
    for (int j = 0; j < NTAG; ++j) trow[j] = trans[i * NTAG + j];
    float fv = (lane == TAG_START) ? 0.0f : NEGV;
    for (int t = 0; t < T_SEQ; ++t) {
        float m = -3.0e38f; int arg = 0;
#pragma unroll
        for (int j = 0; j < NTAG; ++j) {
            float fvj = __shfl(fv, j, 64);
            float sc = fvj + trow[j];
            if (sc > m) { m = sc; arg = j; }
        }
        float ft = feats[((size_t)t * NTAG + i) * 64 + b];
        fv = m + ft;
        if (act) bp[wv][t * NTAG + lane] = (unsigned char)arg;
    }
    float term = act ? (fv + trans[TAG_STOP * NTAG + i]) : -3.0e38f;
    int bi_ = lane;
#pragma unroll
    for (int off = 32; off >= 1; off >>= 1) {
        float ov = __shfl_xor(term, off, 64);
        int oi = __shfl_xor(bi_, off, 64);
        if (ov > term || (ov == term && oi < bi_)) { term = ov; bi_ = oi; }
    }
    if (lane == 0) {
        out[b] = term;
        int tag = bi_;
        float* po = out + 64 + (size_t)b * T_SEQ;
        for (int t = T_SEQ - 1; t >= 0; --t) {
            po[t] = (float)tag;
            tag = bp[wv][t * NTAG + tag];
        }
    }
}

extern "C" void kernel_launch(void* const* d_in, const int* in_sizes, int n_in,
                              void* d_out, int out_size, void* d_ws, size_t ws_size,
                              hipStream_t stream)
{
    (void)in_sizes; (void)n_in; (void)out_size;
    const int*   x     = (const int*)d_in[0];
    const float* emb   = (const float*)d_in[1];
    const float* Wout  = (const float*)d_in[2];
    const float* bout  = (const float*)d_in[3];
    const float* trans = (const float*)d_in[4];

    float* ws = (float*)d_ws;
    const size_t XS2F = (size_t)T_SEQ * 600 * NBATCH;          // f32
    const size_t XS1U = (size_t)T_SEQ * 80 * 64 * 16;          // u16
    const size_t FEA  = (size_t)T_SEQ * NTAG * NBATCH;

    float* xs2 = ws;                          // layer-1 f32 output (aliases xs0 blocks)
    u16* xs0 = (u16*)ws;                      // [T][40][64][2][8]
    u16* xs1 = (u16*)(ws + XS2F);             // [T][80][64][2][8]
    float* featB = (float*)(xs1 + XS1U);
    float* cB = featB + FEA;                  // 2*300*64
    u16* hxB = (u16*)(cB + 2 * 300 * 64);     // 4*HXE
    unsigned* flagsB = (unsigned*)(hxB + 4 * HXE);   // 64 slots * 2 dirs * FLGDIR
    unsigned* padB = flagsB + 64ULL * 2 * FLGDIR;    // 16 u32 of 0xFF
    float* preBase = (float*)(padB + 16);
    size_t fixedBytes = (size_t)((char*)preBase - (char*)ws);

    // two ping-pong pre slots; each slot = preF+preB = 2*Cmax*G4*64 floats
    int Cmax = 512;
    while (Cmax > 16 && fixedBytes + 4ULL * Cmax * G4 * NBATCH * 4ULL > ws_size) Cmax >>= 1;
    size_t slotF = 2ULL * Cmax * G4 * NBATCH;
    float* preS[2] = { preBase, preBase + slotF };

    // chunk schedule: small first chunk shrinks the exposed standalone pregemm
    int sizes[40], off[41], nch = 0;
    {
        int rem = T_SEQ;
        int f = (Cmax >= 64) ? 32 : Cmax;
        sizes[nch++] = f; rem -= f;
        while (rem > 0) { int s = rem < Cmax ? rem : Cmax; sizes[nch++] = s; rem -= s; }
        off[0] = 0;
        for (int i = 0; i < nch; ++i) off[i + 1] = off[i] + sizes[i];
    }

    (void)hipMemsetAsync(hxB, 0,
        4 * HXE * sizeof(u16) + (64ULL * 2 * FLGDIR) * sizeof(unsigned), stream);
    (void)hipMemsetAsync(padB, 0xFF, 16 * sizeof(unsigned), stream);
    k_gather<<<T_SEQ, 256, 0, stream>>>(x, emb, xs0);
    k_zpad<<<T_SEQ, 256, 0, stream>>>(xs1);

    for (int layer = 0; layer < 2; ++layer) {
        int base = 5 + layer * 8;
        const float* WiF = (const float*)d_in[base + 0];
        const float* WhF = (const float*)d_in[base + 1];
        const float* biF = (const float*)d_in[base + 2];
        const float* bhF = (const float*)d_in[base + 3];
        const float* WiB = (const float*)d_in[base + 4];
        const float* WhB = (const float*)d_in[base + 5];
        const float* biB = (const float*)d_in[base + 6];
        const float* bhB = (const float*)d_in[base + 7];

        int NSL0 = (sizes[0] + 31) / 32;
        if (layer == 0)
            k_pregemm<10, 300><<<75 * 2 * NSL0, 256, 0, stream>>>(
                xs0, WiF, WiB, biF, bhF, biB, bhB,
                preS[0], preS[0] + slotF / 2, 0, T_SEQ - 1, NSL0, sizes[0]);
        else
            k_pregemm<20, 600><<<75 * 2 * NSL0, 256, 0, stream>>>(
                xs1, WiF, WiB, biF, bhF, biB, bhB,
                preS[0], preS[0] + slotF / 2, 0, T_SEQ - 1, NSL0, sizes[0]);

        for (int ci = 0; ci < nch; ++ci) {
            int cur = ci & 1, nxt = cur ^ 1;
            int t0f = off[ci], t0b = (T_SEQ - 1) - off[ci];
            int do_pre = (ci + 1 < nch) ? 1 : 0;
            int CN = do_pre ? sizes[ci + 1] : 0;
            int t0fN = off[ci + 1], t0bN = (T_SEQ - 1) - off[ci + 1];
            int slot = layer * 32 + ci;
            unsigned* flags = flagsB + (size_t)slot * 2 * FLGDIR;
            if (layer == 0)
                k_chunk<10, 300, 1><<<2 * NWGD + NPREW, 256, 0, stream>>>(
                    xs0, WiF, WiB, biF, bhF, biB, bhB,
                    preS[nxt], preS[nxt] + slotF / 2, t0fN, t0bN, do_pre, CN,
                    preS[cur], preS[cur] + slotF / 2, WhF, WhB, hxB, cB,
                    xs2, xs1, t0f, t0b, sizes[ci], (ci == 0) ? 1 : 0, flags, padB);
            else
                k_chunk<20, 600, 0><<<2 * NWGD + NPREW, 256, 0, stream>>>(
                    xs1, WiF, WiB, biF, bhF, biB, bhB,
                    preS[nxt], preS[nxt] + slotF / 2, t0fN, t0bN, do_pre, CN,
                    preS[cur], preS[cur] + slotF / 2, WhF, WhB, hxB, cB,
                    xs2, xs1, t0f, t0b, sizes[ci], (ci == 0) ? 1 : 0, flags, padB);
        }
    }
    k_feats<<<T_SEQ, 256, 0, stream>>>(xs2, Wout, bout, featB);
    k_viterbi<<<16, 256, 0, stream>>>(featB, trans, (float*)d_out);
}

// Round 4
// 5896.467 us; speedup vs baseline: 1.1506x; 1.0844x over previous
//
#include <hip/hip_runtime.h>
#include <hip/hip_bf16.h>

#define T_SEQ 512
#define NBATCH 64
#define HID 300
#define G4 1200
#define NTAG 11
#define TAG_START 9
#define TAG_STOP 10
#define NEGV -10000.0f
#define NWGD 38             // lstm WGs per direction, 8 hidden units (= 1 kblock) each
#define NKT 10              // k-tiles of 32 (K padded 300->320)
#define HXE (40*2*64*8)     // u16 per (dir,pp) hx buffer: 40 kblocks x {hi,lo} x 64 b x 8
#define NPREW 150           // companion pregemm WGs
#define FLGS 16             // u32 stride between flags (64B slots)
#define FLGN 152            // flags per dir = 38 WGs x 4 waves
#define FLGDIR (FLGN*FLGS)

typedef unsigned short u16;
using short8 = __attribute__((ext_vector_type(8))) short;
using f32x4  = __attribute__((ext_vector_type(4))) float;
using i32x4  = __attribute__((ext_vector_type(4))) int;

#define MF(a, b, c) __builtin_amdgcn_mfma_f32_16x16x32_bf16((a), (b), (c), 0, 0, 0)

__device__ __forceinline__ float sigf(float x) { return 1.0f / (1.0f + expf(-x)); }

__device__ __forceinline__ u16 f2bf(float x) {
    unsigned u = __float_as_uint(x);
    unsigned r = (u + 0x7FFFu + ((u >> 16) & 1u)) >> 16;   // RNE
    return (u16)r;
}
__device__ __forceinline__ float bf2f(u16 h) {
    return __uint_as_float((unsigned)h << 16);
}

// ---- LLC-coherent (fabric point) helpers: sc0 sc1, no cache-maintenance ops ----
__device__ __forceinline__ i32x4 ld_cc_x4(const u16* p) {
    i32x4 r;
    asm volatile("global_load_dwordx4 %0, %1, off sc0 sc1" : "=v"(r) : "v"(p) : "memory");
    return r;
}
__device__ __forceinline__ unsigned ld_cc_b32(const unsigned* p) {
    unsigned r;
    asm volatile("global_load_dword %0, %1, off sc0 sc1\n\t"
                 "s_waitcnt vmcnt(0)" : "=v"(r) : "v"(p) : "memory");
    return r;
}
__device__ __forceinline__ void st_cc_x4(u16* p, i32x4 v) {
    asm volatile("global_store_dwordx4 %0, %1, off sc0 sc1" :: "v"(p), "v"(v) : "memory");
}
__device__ __forceinline__ void st_cc_b32(unsigned* p, unsigned v) {
    asm volatile("global_store_dword %0, %1, off sc0 sc1" :: "v"(p), "v"(v) : "memory");
}
__device__ __forceinline__ void wait_vm0() {
    asm volatile("s_waitcnt vmcnt(0)" ::: "memory");
}

// ---------- embedding gather -> block layout xs0[t][40][64][2][8] (hi8|lo8 u16) ----------
__global__ __launch_bounds__(256) void k_gather(const int* __restrict__ x,
                                                const float* __restrict__ emb,
                                                u16* __restrict__ xs0)
{
    int t = blockIdx.x;
    __shared__ int rid[NBATCH];
    if (threadIdx.x < NBATCH) rid[threadIdx.x] = x[threadIdx.x * T_SEQ + t];
    __syncthreads();
    for (int o = threadIdx.x; o < 64 * 40; o += 256) {
        int b = o / 40, m8 = o - b * 40;
        unsigned hw[4], lw[4];
#pragma unroll
        for (int p = 0; p < 4; ++p) {
            int k0 = m8 * 8 + p * 2;
            float v0 = (k0 < 300)     ? emb[(size_t)rid[b] * 300 + k0]     : 0.0f;
            float v1 = (k0 + 1 < 300) ? emb[(size_t)rid[b] * 300 + k0 + 1] : 0.0f;
            u16 h0 = f2bf(v0), h1 = f2bf(v1);
            u16 l0 = f2bf(v0 - bf2f(h0)), l1 = f2bf(v1 - bf2f(h1));
            hw[p] = (unsigned)h0 | ((unsigned)h1 << 16);
            lw[p] = (unsigned)l0 | ((unsigned)l1 << 16);
        }
        u16* dst = xs0 + (((size_t)t * 40 + m8) * 64 + b) * 16;
        *(i32x4*)dst       = i32x4{(int)hw[0], (int)hw[1], (int)hw[2], (int)hw[3]};
        *(i32x4*)(dst + 8) = i32x4{(int)lw[0], (int)lw[1], (int)lw[2], (int)lw[3]};
    }
}

// ---------- zero xs1 pad blocks 76..79 ----------
__global__ __launch_bounds__(256) void k_zpad(u16* __restrict__ xs1)
{
    int t = blockIdx.x;
    i32x4* base = (i32x4*)(xs1 + (((size_t)t * 80 + 76) * 64) * 16);
    i32x4 z = {0, 0, 0, 0};
    for (int o = threadIdx.x; o < 4 * 64 * 2; o += 256) base[o] = z;
}

// ---------- pregemm core (device): one (jtile,dir), timesteps [s0,s1) ----------
template<int KT, int KMAX>
__device__ __forceinline__ void pregemm_role(
    const u16* __restrict__ xs,
    const float* __restrict__ Wi, const float* __restrict__ bi, const float* __restrict__ bh,
    float* __restrict__ pre, int jtile, int dir, int t0f, int t0b, int s0, int s1, int tid)
{
    int w = tid >> 6, l = tid & 63;
    int hh = l >> 4, kbx = l >> 4;
    int jj = jtile * 4 + hh;
    int bcol = w * 16 + (l & 15);

    short8 aH[KT], aL[KT];
    {
        int r = l & 15;
        int g = r & 3, uo = r >> 2;
        const float* wr = Wi + ((size_t)g * 300 + jtile * 4 + uo) * KMAX;
        int kb0 = kbx * 8;
#pragma unroll
        for (int kt = 0; kt < KT; ++kt) {
            short8 vh, vl;
#pragma unroll
            for (int e = 0; e < 8; ++e) {
                int kp = kt * 32 + kb0 + e;
                bool valid; int cc;
                if (KMAX == 600) { valid = (kp < 300) || (kp >= 304 && kp < 604); cc = (kp < 300) ? kp : kp - 4; }
                else             { valid = (kp < 300); cc = kp; }
                float wv = valid ? wr[cc] : 0.0f;
                u16 hb = f2bf(wv);
                vh[e] = (short)hb;
                vl[e] = (short)f2bf(wv - bf2f(hb));
            }
            aH[kt] = vh; aL[kt] = vl;
        }
    }
    float bias[4];
#pragma unroll
    for (int q = 0; q < 4; ++q) bias[q] = bi[q * 300 + jj] + bh[q * 300 + jj];

    const int NB8 = KT * 4;
    for (int s = s0; s < s1; ++s) {
        int t = dir ? (t0b - s) : (t0f + s);
        f32x4 a0 = {0.f,0.f,0.f,0.f}, a1 = {0.f,0.f,0.f,0.f}, a2 = {0.f,0.f,0.f,0.f};
#pragma unroll
        for (int kt = 0; kt < KT; ++kt) {
            const u16* gx = xs + (((size_t)t * NB8 + (4 * kt + kbx)) * 64 + bcol) * 16;
            short8 bhv = *(const short8*)gx;
            short8 blv = *(const short8*)(gx + 8);
            a0 = MF(aH[kt], bhv, a0);
            a1 = MF(aL[kt], bhv, a1);
            a2 = MF(aH[kt], blv, a2);
        }
#pragma unroll
        for (int q = 0; q < 4; ++q)
            pre[((size_t)s * G4 + q * 300 + jj) * 64 + bcol] = a0[q] + a1[q] + a2[q] + bias[q];
    }
}

// ---------- standalone pregemm (chunk 0 of each layer): sliced grid ----------
template<int KT, int KMAX>
__global__ __launch_bounds__(256) void k_pregemm(
    const u16* __restrict__ xs,
    const float* __restrict__ WiF, const float* __restrict__ WiB,
    const float* __restrict__ biF, const float* __restrict__ bhF,
    const float* __restrict__ biB, const float* __restrict__ bhB,
    float* __restrict__ preF, float* __restrict__ preB,
    int t0f, int t0b, int NSL, int C)
{
    int bx = blockIdx.x;
    int idx = bx / (2 * NSL);
    int rem = bx - idx * 2 * NSL;
    int sl = rem >> 1, dir = rem & 1;
    int s0 = sl * 32, s1 = min(s0 + 32, C);
    pregemm_role<KT, KMAX>(xs,
        dir ? WiB : WiF, dir ? biB : biF, dir ? bhB : bhF,
        dir ? preB : preF, idx, dir, t0f, t0b, s0, s1, threadIdx.x);
}

// ---------- lstm role: wave-autonomous flags + plane-split exchange ----------
// hx per (dir,pp): [kblock 0..39][plane hi/lo][batch 0..63][8 u16].
// Poll is SHARDED across the WG's 4 waves: wave w polls flags [38w,38w+38)
// of its direction (one per lane), publishes its shard's certified step to
// an LDS monotone counter, and all waves spin on the 4 LDS counters. The
// wait condition (all 152 same-dir wave flags >= tgt) is identical to the
// proven baseline; readers per flag LINE drop 152 -> 38, and per-iteration
// device-scope poll loads drop ~5x. Flag layout/stores unchanged (1 writer
// per 64B line — round 1 showed multi-writer lines regress).
template<int MODE>
__device__ __forceinline__ void lstm_role(
    const float* __restrict__ preF, const float* __restrict__ preB,
    const float* __restrict__ WhF, const float* __restrict__ WhB,
    u16* __restrict__ hx, float* __restrict__ cbuf,
    float* __restrict__ xs2, u16* __restrict__ xs1,
    int t0f, int t0b, int C, int first,
    unsigned* __restrict__ flags,
    volatile unsigned* wgprog,
    int bid, int tid)
{
    __builtin_amdgcn_s_setprio(1);
    int dir = bid & 1, idx = bid >> 1;   // idx 0..37
    const float* pre = dir ? preB : preF;
    const float* Wh  = dir ? WhB : WhF;
    u16* hxd = hx + (size_t)dir * 2 * HXE;
    float* cb = cbuf + (size_t)dir * 300 * 64;
    unsigned* flg = flags + (size_t)dir * FLGDIR;
    int w = tid >> 6, l = tid & 63;
    int hh = l >> 4, kbx = l >> 4;
    int bcol = w * 16 + (l & 15);
    int j0 = idx * 8;
    int ju0 = j0 + hh, ju1 = j0 + 4 + hh;
    int jc0 = min(ju0, 299), jc1 = min(ju1, 299);
    bool jv0 = ju0 < 300, jv1 = ju1 < 300;

    unsigned* myflag = flg + (size_t)(idx * 4 + w) * FLGS;
    // shard poll: wave w covers flags [38w, 38w+38), lane i -> flag 38w+i
    const unsigned* shardp = flg + (size_t)(w * 38 + min(l, 37)) * FLGS;
    bool shact = l < 38;

    // LDS shard-progress init (monotone counters; one-time barrier)
    if (l == 0) wgprog[w] = 0;
    __syncthreads();

    // A fragments (2 stripes x hi/lo), preloaded once
    short8 aH[2][NKT], aL[2][NKT];
    {
        int r = l & 15;
        int g = r & 3, uo = r >> 2;
#pragma unroll
        for (int q = 0; q < 2; ++q) {
            int jr = j0 + q * 4 + uo;
            const float* wr = Wh + ((size_t)g * 300 + min(jr, 299)) * 300;
            bool jvr = jr < 300;
#pragma unroll
            for (int kt = 0; kt < NKT; ++kt) {
                short8 vh, vl;
#pragma unroll
                for (int e = 0; e < 8; ++e) {
                    int k = kt * 32 + kbx * 8 + e;
                    float wv = (jvr && k < 300) ? wr[k] : 0.0f;
                    u16 hb = f2bf(wv);
                    vh[e] = (short)hb;
                    vl[e] = (short)f2bf(wv - bf2f(hb));
                }
                aH[q][kt] = vh; aL[q][kt] = vl;
            }
        }
    }
    float c0 = first ? 0.0f : cb[(size_t)jc0 * 64 + bcol];
    float c1 = first ? 0.0f : cb[(size_t)jc1 * 64 + bcol];

    float p0[4], p1[4];
#pragma unroll
    for (int g = 0; g < 4; ++g) {
        p0[g] = pre[((size_t)g * 300 + jc0) * 64 + bcol];
        p1[g] = pre[((size_t)g * 300 + jc1) * 64 + bcol];
    }

    int pp = 0;
    for (int s = 0; s < C; ++s) {
        f32x4 aA0 = {0.f,0.f,0.f,0.f}, aB0 = {0.f,0.f,0.f,0.f}, aC0 = {0.f,0.f,0.f,0.f};
        f32x4 aA1 = {0.f,0.f,0.f,0.f}, aB1 = {0.f,0.f,0.f,0.f}, aC1 = {0.f,0.f,0.f,0.f};
        if (!(first && s == 0)) {
            const u16* hxr = hxd + (size_t)pp * HXE;
            i32x4 bh[NKT], bl[NKT];
#pragma unroll
            for (int kt = 0; kt < NKT; ++kt) {
                const u16* gp = hxr + (size_t)(4 * kt + kbx) * 1024 + (size_t)bcol * 8;
                bh[kt] = ld_cc_x4(gp);
            }
#pragma unroll
            for (int kt = 0; kt < NKT; ++kt) {
                const u16* gp = hxr + (size_t)(4 * kt + kbx) * 1024 + (size_t)bcol * 8;
                bl[kt] = ld_cc_x4(gp + 512);
            }
            // hi plane ready (10 lo still in flight)
            asm volatile("s_waitcnt vmcnt(10)" ::: "memory");
            __builtin_amdgcn_sched_barrier(0);
#pragma unroll
            for (int kt = 0; kt < NKT; ++kt) {
                short8 bhv = __builtin_bit_cast(short8, bh[kt]);
                aA0 = MF(aH[0][kt], bhv, aA0);
                aB0 = MF(aL[0][kt], bhv, aB0);
                aA1 = MF(aH[1][kt], bhv, aA1);
                aB1 = MF(aL[1][kt], bhv, aB1);
            }
            wait_vm0();
            __builtin_amdgcn_sched_barrier(0);
#pragma unroll
            for (int kt = 0; kt < NKT; ++kt) {
                short8 blv = __builtin_bit_cast(short8, bl[kt]);
                aC0 = MF(aH[0][kt], blv, aC0);
                aC1 = MF(aH[1][kt], blv, aC1);
            }
        }
        float hv0, hv1;
        {
            float gi = sigf(aA0[0] + aB0[0] + aC0[0] + p0[0]);
            float gf = sigf(aA0[1] + aB0[1] + aC0[1] + p0[1]);
            float gg = tanhf(aA0[2] + aB0[2] + aC0[2] + p0[2]);
            float go = sigf(aA0[3] + aB0[3] + aC0[3] + p0[3]);
            c0 = gf * c0 + gi * gg;
            hv0 = go * tanhf(c0);
            if (!jv0) hv0 = 0.0f;
        }
        {
            float gi = sigf(aA1[0] + aB1[0] + aC1[0] + p1[0]);
            float gf = sigf(aA1[1] + aB1[1] + aC1[1] + p1[1]);
            float gg = tanhf(aA1[2] + aB1[2] + aC1[2] + p1[2]);
            float go = sigf(aA1[3] + aB1[3] + aC1[3] + p1[3]);
            c1 = gf * c1 + gi * gg;
            hv1 = go * tanhf(c1);
            if (!jv1) hv1 = 0.0f;
        }
        u16 hb0 = f2bf(hv0);
        unsigned pk0 = (unsigned)hb0 | ((unsigned)f2bf(hv0 - bf2f(hb0)) << 16);
        u16 hb1 = f2bf(hv1);
        unsigned pk1 = (unsigned)hb1 | ((unsigned)f2bf(hv1 - bf2f(hb1)) << 16);
        int ls = l & 15;
        unsigned a0 = __shfl(pk0, ls), a1 = __shfl(pk0, ls + 16), a2 = __shfl(pk0, ls + 32), a3 = __shfl(pk0, ls + 48);
        unsigned b0 = __shfl(pk1, ls), b1 = __shfl(pk1, ls + 16), b2 = __shfl(pk1, ls + 32), b3 = __shfl(pk1, ls + 48);
        i32x4 hi4 = {(int)((a0 & 0xffffu) | (a1 << 16)), (int)((a2 & 0xffffu) | (a3 << 16)),
                     (int)((b0 & 0xffffu) | (b1 << 16)), (int)((b2 & 0xffffu) | (b3 << 16))};
        i32x4 lo4 = {(int)((a0 >> 16) | (a1 & 0xffff0000u)), (int)((a2 >> 16) | (a3 & 0xffff0000u)),
                     (int)((b0 >> 16) | (b1 & 0xffff0000u)), (int)((b2 >> 16) | (b3 & 0xffff0000u))};
        int t = dir ? (t0b - s) : (t0f + s);
        // exchange stores (plane-split), wave-local drain, own flag — no syncthreads
        if (l < 16) {
            int b = w * 16 + l;
            u16* hxw = hxd + (size_t)(pp ^ 1) * HXE + (size_t)idx * 1024 + (size_t)b * 8;
            st_cc_x4(hxw, hi4);
            st_cc_x4(hxw + 512, lo4);
        }
        wait_vm0();
        if (l == 0) st_cc_b32(myflag, (unsigned)(s + 1));
        // xs output + next-step pre prefetch (drain under the poll)
        if (MODE == 0) {
            if (jv0) xs2[((size_t)t * 600 + dir * 300 + ju0) * 64 + bcol] = hv0;
            if (jv1) xs2[((size_t)t * 600 + dir * 300 + ju1) * 64 + bcol] = hv1;
        } else if (l < 16) {
            int b = w * 16 + l;
            u16* xd = xs1 + (((size_t)t * 80 + dir * 38 + idx) * 64 + b) * 16;
            *(i32x4*)xd       = hi4;
            *(i32x4*)(xd + 8) = lo4;
        }
        if (s + 1 < C) {
#pragma unroll
            for (int g = 0; g < 4; ++g) {
                p0[g] = pre[((size_t)(s + 1) * G4 + (size_t)g * 300 + jc0) * 64 + bcol];
                p1[g] = pre[((size_t)(s + 1) * G4 + (size_t)g * 300 + jc1) * 64 + bcol];
            }
            unsigned tgt = (unsigned)(s + 1);
            // 1) poll own shard (38 flags, one per lane)
            unsigned ok;
            do {
                unsigned v = tgt;
                if (shact) v = ld_cc_b32(shardp);
                ok = (v >= tgt) ? 1u : 0u;
            } while (!__all(ok));
            // 2) publish shard progress, 3) wait for sibling shards (LDS only)
            if (l == 0) wgprog[w] = tgt;
            while (!(wgprog[0] >= tgt && wgprog[1] >= tgt &&
                     wgprog[2] >= tgt && wgprog[3] >= tgt)) {
                __builtin_amdgcn_s_sleep(1);
            }
        }
        pp ^= 1;
    }
    if (jv0) cb[(size_t)jc0 * 64 + bcol] = c0;
    if (jv1) cb[(size_t)jc1 * 64 + bcol] = c1;
}

// ---------- fused chunk kernel: 76 lstm WGs + 150 companion pregemm WGs ----------
template<int KT, int KMAX, int MODE>
__global__ __launch_bounds__(256, 1) void k_chunk(
    const u16* __restrict__ xsN,
    const float* __restrict__ WiF, const float* __restrict__ WiB,
    const float* __restrict__ biF, const float* __restrict__ bhF,
    const float* __restrict__ biB, const float* __restrict__ bhB,
    float* __restrict__ preNF, float* __restrict__ preNB,
    int t0fN, int t0bN, int do_pre, int CN,
    const float* __restrict__ preF, const float* __restrict__ preB,
    const float* __restrict__ WhF, const float* __restrict__ WhB,
    u16* __restrict__ hx, float* __restrict__ cbuf,
    float* __restrict__ xs2, u16* __restrict__ xs1,
    int t0f, int t0b, int C, int first,
    unsigned* __restrict__ flags)
{
    __shared__ unsigned wgprog[4];
    int bid = blockIdx.x;
    if (bid < 2 * NWGD) {
        lstm_role<MODE>(preF, preB, WhF, WhB, hx, cbuf, xs2, xs1,
                        t0f, t0b, C, first, flags, wgprog, bid, threadIdx.x);
    } else if (do_pre) {
        int wg = bid - 2 * NWGD;         // 0..149
        int jtile = wg >> 1, dir = wg & 1;
        pregemm_role<KT, KMAX>(xsN,
            dir ? WiB : WiF, dir ? biB : biF, dir ? bhB : bhF,
            dir ? preNB : preNF, jtile, dir, t0fN, t0bN, 0, CN, threadIdx.x);
    }
}

// ---------- output projection: feats[t][g][b] ----------
__global__ __launch_bounds__(256) void k_feats(
    const float* __restrict__ xs2, const float* __restrict__ Wout,
    const float* __restrict__ bout, float* __restrict__ feats)
{
    int t = blockIdx.x;
    int tid = threadIdx.x;
    int b = tid & 63, g0 = tid >> 6;
    const float* xa = xs2 + (size_t)t * 600 * 64 + b;
    for (int g = g0; g < NTAG; g += 4) {
        float acc = bout[g];
        const float* wr = Wout + (size_t)g * 600;
#pragma unroll 4
        for (int k = 0; k < 600; ++k) acc += wr[k] * xa[(size_t)k * 64];
        feats[((size_t)t * NTAG + g) * 64 + b] = acc;
    }
}

// ---------- Viterbi ----------
__global__ __launch_bounds__(256) void k_viterbi(
    const float* __restrict__ feats, const float* __restrict__ trans,
    float* __restrict__ out)
{
    __shared__ unsigned char bp[4][T_SEQ * NTAG];
    int tid = threadIdx.x;
    int wv = tid >> 6, lane = tid & 63;
    int b = blockIdx.x * 4 + wv;
    int i = (lane < NTAG) ? lane : 0;
    bool act = lane < NTAG;
    float trow[NTAG];
#pragma unroll
    for (int j = 0; j < NTAG; ++j) trow[j] = trans[i * NTAG + j];
    float fv = (lane == TAG_START) ? 0.0f : NEGV;
    for (int t = 0; t < T_SEQ; ++t) {
        float m = -3.0e38f; int arg = 0;
#pragma unroll
        for (int j = 0; j < NTAG; ++j) {
            float fvj = __shfl(fv, j, 64);
            float sc = fvj + trow[j];
            if (sc > m) { m = sc; arg = j; }
        }
        float ft = feats[((size_t)t * NTAG + i) * 64 + b];
        fv = m + ft;
        if (act) bp[wv][t * NTAG + lane] = (unsigned char)arg;
    }
    float term = act ? (fv + trans[TAG_STOP * NTAG + i]) : -3.0e38f;
    int bi_ = lane;
#pragma unroll
    for (int off = 32; off >= 1; off >>= 1) {
        float ov = __shfl_xor(term, off, 64);
        int oi = __shfl_xor(bi_, off, 64);
        if (ov > term || (ov == term && oi < bi_)) { term = ov; bi_ = oi; }
    }
    if (lane == 0) {
        out[b] = term;
        int tag = bi_;
        float* po = out + 64 + (size_t)b * T_SEQ;
        for (int t = T_SEQ - 1; t >= 0; --t) {
            po[t] = (float)tag;
            tag = bp[wv][t * NTAG + tag];
        }
    }
}

extern "C" void kernel_launch(void* const* d_in, const int* in_sizes, int n_in,
                              void* d_out, int out_size, void* d_ws, size_t ws_size,
                              hipStream_t stream)
{
    (void)in_sizes; (void)n_in; (void)out_size;
    const int*   x     = (const int*)d_in[0];
    const float* emb   = (const float*)d_in[1];
    const float* Wout  = (const float*)d_in[2];
    const float* bout  = (const float*)d_in[3];
    const float* trans = (const float*)d_in[4];

    float* ws = (float*)d_ws;
    const size_t XS2F = (size_t)T_SEQ * 600 * NBATCH;          // f32
    const size_t XS1U = (size_t)T_SEQ * 80 * 64 * 16;          // u16
    const size_t FEA  = (size_t)T_SEQ * NTAG * NBATCH;

    float* xs2 = ws;                          // layer-1 f32 output (aliases xs0 blocks)
    u16* xs0 = (u16*)ws;                      // [T][40][64][2][8]
    u16* xs1 = (u16*)(ws + XS2F);             // [T][80][64][2][8]
    float* featB = (float*)(xs1 + XS1U);
    float* cB = featB + FEA;                  // 2*300*64
    u16* hxB = (u16*)(cB + 2 * 300 * 64);     // 4*HXE
    unsigned* flagsB = (unsigned*)(hxB + 4 * HXE);   // 64 slots * 2 dirs * FLGDIR
    unsigned* padB = flagsB + 64ULL * 2 * FLGDIR;    // layout hole kept (16 u32)
    float* preBase = (float*)(padB + 16);
    size_t fixedBytes = (size_t)((char*)preBase - (char*)ws);

    // two ping-pong pre slots; each slot = preF+preB = 2*Cmax*G4*64 floats
    int Cmax = 512;
    while (Cmax > 16 && fixedBytes + 4ULL * Cmax * G4 * NBATCH * 4ULL > ws_size) Cmax >>= 1;
    size_t slotF = 2ULL * Cmax * G4 * NBATCH;
    float* preS[2] = { preBase, preBase + slotF };

    // chunk schedule: small first chunk shrinks the exposed standalone pregemm
    int sizes[40], off[41], nch = 0;
    {
        int rem = T_SEQ;
        int f = (Cmax >= 64) ? 32 : Cmax;
        sizes[nch++] = f; rem -= f;
        while (rem > 0) { int s = rem < Cmax ? rem : Cmax; sizes[nch++] = s; rem -= s; }
        off[0] = 0;
        for (int i = 0; i < nch; ++i) off[i + 1] = off[i] + sizes[i];
    }

    (void)hipMemsetAsync(hxB, 0,
        4 * HXE * sizeof(u16) + (64ULL * 2 * FLGDIR) * sizeof(unsigned), stream);
    k_gather<<<T_SEQ, 256, 0, stream>>>(x, emb, xs0);
    k_zpad<<<T_SEQ, 256, 0, stream>>>(xs1);

    for (int layer = 0; layer < 2; ++layer) {
        int base = 5 + layer * 8;
        const float* WiF = (const float*)d_in[base + 0];
        const float* WhF = (const float*)d_in[base + 1];
        const float* biF = (const float*)d_in[base + 2];
        const float* bhF = (const float*)d_in[base + 3];
        const float* WiB = (const float*)d_in[base + 4];
        const float* WhB = (const float*)d_in[base + 5];
        const float* biB = (const float*)d_in[base + 6];
        const float* bhB = (const float*)d_in[base + 7];

        int NSL0 = (sizes[0] + 31) / 32;
        if (layer == 0)
            k_pregemm<10, 300><<<75 * 2 * NSL0, 256, 0, stream>>>(
                xs0, WiF, WiB, biF, bhF, biB, bhB,
                preS[0], preS[0] + slotF / 2, 0, T_SEQ - 1, NSL0, sizes[0]);
        else
            k_pregemm<20, 600><<<75 * 2 * NSL0, 256, 0, stream>>>(
                xs1, WiF, WiB, biF, bhF, biB, bhB,
                preS[0], preS[0] + slotF / 2, 0, T_SEQ - 1, NSL0, sizes[0]);

        for (int ci = 0; ci < nch; ++ci) {
            int cur = ci & 1, nxt = cur ^ 1;
            int t0f = off[ci], t0b = (T_SEQ - 1) - off[ci];
            int do_pre = (ci + 1 < nch) ? 1 : 0;
            int CN = do_pre ? sizes[ci + 1] : 0;
            int t0fN = off[ci + 1], t0bN = (T_SEQ - 1) - off[ci + 1];
            int slot = layer * 32 + ci;
            unsigned* flags = flagsB + (size_t)slot * 2 * FLGDIR;
            if (layer == 0)
                k_chunk<10, 300, 1><<<2 * NWGD + NPREW, 256, 0, stream>>>(
                    xs0, WiF, WiB, biF, bhF, biB, bhB,
                    preS[nxt], preS[nxt] + slotF / 2, t0fN, t0bN, do_pre, CN,
                    preS[cur], preS[cur] + slotF / 2, WhF, WhB, hxB, cB,
                    xs2, xs1, t0f, t0b, sizes[ci], (ci == 0) ? 1 : 0, flags);
            else
                k_chunk<20, 600, 0><<<2 * NWGD + NPREW, 256, 0, stream>>>(
                    xs1, WiF, WiB, biF, bhF, biB, bhB,
                    preS[nxt], preS[nxt] + slotF / 2, t0fN, t0bN, do_pre, CN,
                    preS[cur], preS[cur] + slotF / 2, WhF, WhB, hxB, cB,
                    xs2, xs1, t0f, t0b, sizes[ci], (ci == 0) ? 1 : 0, flags);
        }
    }
    k_feats<<<T_SEQ, 256, 0, stream>>>(xs2, Wout, bout, featB);
    k_viterbi<<<16, 256, 0, stream>>>(featB, trans, (float*)d_out);
}